// Round 8
// baseline (54.432 us; speedup 1.0000x reference)
//
#include <hip/hip_runtime.h>
#include <hip/hip_cooperative_groups.h>

namespace cg = cooperative_groups;

namespace {
constexpr int B_ = 4;
constexpr int N_ = 240 * 320;      // 76800 pixels per image (C == 1)
constexpr int M_ = 256;            // bins
constexpr int PXB = 1024;          // pixels per block
constexpr int CHUNKS = N_ / PXB;   // 75 blocks per batch
constexpr int NBLK = B_ * CHUNKS;  // 300 blocks (co-resident: 2 blocks/CU needed, LDS allows 9)
constexpr int NI = M_ + 1;         // 257 value-intervals
constexpr float BIG = 3.0e38f;
constexpr unsigned POISON = 0xAAAAAAAAu;

// ws words. Plain slots are overwritten every call (deterministic).
//   WS_T2B  [NBLK]   per-block t2b partial sums   (plain store)
//   WS_MAXP [NBLK]   per-block pixel maxima       (plain store)
//   WS_SORT [B_*M_]  sorted bins                  (plain store, chunk-0 blocks)
//   WS_GMIN [B_*NI]  per-interval min pixel bits  (atomicMin; harness poison
//       0xAAAAAAAA > any +float bits -> acts as empty; idempotent on replays)
//   WS_GMAX [B_*NI]  NEGATED max pixel bits       (atomicMax; poison loses too)
constexpr int WS_T2B = 0;
constexpr int WS_MAXP = NBLK;
constexpr int WS_SORT = 2 * NBLK;
constexpr int WS_GMIN = 2 * NBLK + B_ * M_;
constexpr int WS_GMAX = WS_GMIN + B_ * NI;
}  // namespace

// Raw-value math: (c/m - t/m)^2 == (c-t)^2 / m^2; normalization deferred to the
// finisher (validated R5-R7: absmax 0.0).
__global__ __launch_bounds__(512) void chamfer_coop_kernel(const float* __restrict__ target,
                                                           const float* __restrict__ bins,
                                                           unsigned* __restrict__ wsu,
                                                           float* __restrict__ out) {
  float* wsf = reinterpret_cast<float*>(wsu);
  const int bid = blockIdx.x;
  const int b = bid / CHUNKS;
  const int chunk = bid - b * CHUNKS;
  const int tid = threadIdx.x;

  __shared__ __align__(16) float raw[M_];
  __shared__ float sbin[M_];
  __shared__ unsigned imin[NI], imax[NI];
  __shared__ float red[16];
  // finisher-only (block 0); LDS total ~17 KB, fine for co-residency
  __shared__ float pm[B_][NI + 7];
  __shared__ float smn[B_][NI + 7];
  __shared__ float sc[B_][M_];
  __shared__ float rv[16], rt[16], rm[16];

  if (tid < M_) raw[tid] = bins[b * M_ + tid];
  for (int i = tid; i < NI; i += 512) {
    imin[i] = 0x7f800000u;  // +inf bits
    imax[i] = 0u;           // 0.0 bits (all pixels > 0)
  }
  __syncthreads();

  // ---- rank sort of the 256 bins (threads 0..255; deterministic tie-break) ----
  if (tid < M_) {
    const float myv = raw[tid];
    int rank = 0;
    const float4* r4 = reinterpret_cast<const float4*>(raw);
#pragma unroll 4
    for (int k4 = 0; k4 < M_ / 4; ++k4) {
      const float4 v = r4[k4];  // LDS broadcast
      const int k = k4 * 4;
      rank += (v.x < myv || (v.x == myv && k + 0 < tid)) ? 1 : 0;
      rank += (v.y < myv || (v.y == myv && k + 1 < tid)) ? 1 : 0;
      rank += (v.z < myv || (v.z == myv && k + 2 < tid)) ? 1 : 0;
      rank += (v.w < myv || (v.w == myv && k + 3 < tid)) ? 1 : 0;
    }
    sbin[rank] = myv;
  }
  __syncthreads();

  // ---- per-pixel: binary search -> flank distances + interval min/max ----
  const float2 px =
      reinterpret_cast<const float2*>(target + b * N_ + chunk * PXB)[tid];

  float ssum = 0.f;
#pragma unroll
  for (int e = 0; e < 2; ++e) {
    const float t = (e == 0) ? px.x : px.y;
    int pos = 0;  // count of bins <= t  (0..256)
#pragma unroll
    for (int step = 128; step > 0; step >>= 1)
      if (sbin[pos + step - 1] <= t) pos += step;
    if (pos < M_ && sbin[pos] <= t) ++pos;
    // nearest bin is one of the two flanks (sorted => exact)
    float dl = BIG, dr = BIG;
    if (pos > 0)  { const float d = t - sbin[pos - 1]; dl = d * d; }
    if (pos < M_) { const float d = sbin[pos] - t;     dr = d * d; }
    ssum += fminf(dl, dr);
    atomicMin(&imin[pos], __float_as_uint(t));
    atomicMax(&imax[pos], __float_as_uint(t));
  }

  float mx = fmaxf(px.x, px.y);
#pragma unroll
  for (int o = 32; o > 0; o >>= 1) {
    ssum += __shfl_down(ssum, o);
    mx = fmaxf(mx, __shfl_down(mx, o));
  }
  if ((tid & 63) == 0) {
    red[tid >> 6] = ssum;
    red[8 + (tid >> 6)] = mx;
  }
  __syncthreads();

  if (tid == 0) {
    float s = 0.f, m = 0.f;
#pragma unroll
    for (int w = 0; w < 8; ++w) {
      s += red[w];
      m = fmaxf(m, red[8 + w]);
    }
    wsf[WS_T2B + bid] = s;   // plain per-block slots
    wsf[WS_MAXP + bid] = m;
  }

  // flush block-local interval extrema to per-batch global slots
  for (int i = tid; i < NI; i += 512) {
    const unsigned mn = imin[i];
    if (mn != 0x7f800000u) atomicMin(&wsu[WS_GMIN + b * NI + i], mn);
    const unsigned mb = imax[i];
    if (mb != 0u)
      atomicMax(&wsu[WS_GMAX + b * NI + i],
                __float_as_uint(-__uint_as_float(mb)));  // negate: max as uint-max
  }
  if (chunk == 0 && tid < M_) wsf[WS_SORT + b * M_ + tid] = sbin[tid];

  // ---- grid-wide barrier: runtime handles release/acquire coherence once ----
  cg::this_grid().sync();

  if (blockIdx.x != 0) return;

  // =================== finisher (block 0, plain loads) ===================
  for (int i = tid; i < B_ * NI; i += 512) {
    const int bat = i / NI;
    const int k = i - bat * NI;
    const unsigned v = wsu[WS_GMIN + i];
    smn[bat][k] = (v == POISON) ? BIG : __uint_as_float(v);
    const unsigned u = wsu[WS_GMAX + i];
    pm[bat][k] = (u == POISON) ? -BIG : -__uint_as_float(u);
  }
  for (int i = tid; i < B_ * M_; i += 512)
    sc[i >> 8][i & 255] = wsf[WS_SORT + i];
  __syncthreads();

  const int j = tid & 255;
  const int bh = tid >> 8;  // 0..1; this thread owns batches bh and bh+2
  // Hillis-Steele: inclusive prefix-max (pm) / suffix-min (smn) over 257 entries
  for (int off = 1; off <= 256; off <<= 1) {
    const float p0o = pm[bh][j],      p0n = (j >= off) ? pm[bh][j - off] : -BIG;
    const float p1o = pm[bh + 2][j],  p1n = (j >= off) ? pm[bh + 2][j - off] : -BIG;
    const float s0o = smn[bh][j],     s0n = (j + off <= 256) ? smn[bh][j + off] : BIG;
    const float s1o = smn[bh + 2][j], s1n = (j + off <= 256) ? smn[bh + 2][j + off] : BIG;
    __syncthreads();
    pm[bh][j] = fmaxf(p0o, p0n);
    pm[bh + 2][j] = fmaxf(p1o, p1n);
    smn[bh][j] = fminf(s0o, s0n);
    smn[bh + 2][j] = fminf(s1o, s1n);
    __syncthreads();
  }

  // bin j (sorted): below-candidates in intervals 0..j, above in j+1..256
  float vb0, vb1;
  {
    const float c0 = sc[bh][j];
    const float bl = pm[bh][j], ab = smn[bh][j + 1];
    const float d1 = (bl == -BIG) ? BIG : (c0 - bl) * (c0 - bl);
    const float d2 = (ab == BIG) ? BIG : (ab - c0) * (ab - c0);
    vb0 = fminf(d1, d2);
    const float c1 = sc[bh + 2][j];
    const float bl1 = pm[bh + 2][j], ab1 = smn[bh + 2][j + 1];
    const float e1 = (bl1 == -BIG) ? BIG : (c1 - bl1) * (c1 - bl1);
    const float e2 = (ab1 == BIG) ? BIG : (ab1 - c1) * (ab1 - c1);
    vb1 = fminf(e1, e2);
  }
  // t2b partials + maxima (75 per batch), same thread->batch mapping
  float st0 = (j < CHUNKS) ? wsf[WS_T2B + bh * CHUNKS + j] : 0.f;
  float st1 = (j < CHUNKS) ? wsf[WS_T2B + (bh + 2) * CHUNKS + j] : 0.f;
  float sx0 = (j < CHUNKS) ? wsf[WS_MAXP + bh * CHUNKS + j] : 0.f;
  float sx1 = (j < CHUNKS) ? wsf[WS_MAXP + (bh + 2) * CHUNKS + j] : 0.f;
#pragma unroll
  for (int o = 32; o > 0; o >>= 1) {
    vb0 += __shfl_down(vb0, o);
    vb1 += __shfl_down(vb1, o);
    st0 += __shfl_down(st0, o);
    st1 += __shfl_down(st1, o);
    sx0 = fmaxf(sx0, __shfl_down(sx0, o));
    sx1 = fmaxf(sx1, __shfl_down(sx1, o));
  }
  if ((tid & 63) == 0) {
    const int w = tid >> 6;  // 0..7; waves 0-3: bh=0, waves 4-7: bh=1
    rv[w * 2] = vb0; rv[w * 2 + 1] = vb1;
    rt[w * 2] = st0; rt[w * 2 + 1] = st1;
    rm[w * 2] = sx0; rm[w * 2 + 1] = sx1;
  }
  __syncthreads();
  if (tid == 0) {
    // slots: batch0 = waves0-3 even, batch1 = waves4-7 even,
    //        batch2 = waves0-3 odd,  batch3 = waves4-7 odd
    const int base[B_] = {0, 8, 1, 9};
    float loss = 0.f;
#pragma unroll
    for (int bat = 0; bat < B_; ++bat) {
      const int s0 = base[bat];
      float s1 = 0.f, s2 = 0.f, m = 0.f;
#pragma unroll
      for (int w = 0; w < 4; ++w) {
        s1 += rv[s0 + 2 * w];
        s2 += rt[s0 + 2 * w];
        m = fmaxf(m, rm[s0 + 2 * w]);
      }
      const float inv = 1.0f / (m * m);  // deferred normalization
      loss += (s1 / (float)M_) * inv + (s2 / (float)N_) * inv;
    }
    out[0] = loss / (float)B_ * 10.0f;
  }
}

extern "C" void kernel_launch(void* const* d_in, const int* in_sizes, int n_in,
                              void* d_out, int out_size, void* d_ws, size_t ws_size,
                              hipStream_t stream) {
  (void)in_sizes; (void)n_in; (void)out_size; (void)ws_size;
  const float* target = reinterpret_cast<const float*>(d_in[0]);
  const float* bins = reinterpret_cast<const float*>(d_in[1]);
  unsigned* ws = reinterpret_cast<unsigned*>(d_ws);
  float* out = reinterpret_cast<float*>(d_out);

  void* args[] = {(void*)&target, (void*)&bins, (void*)&ws, (void*)&out};
  hipLaunchCooperativeKernel(reinterpret_cast<const void*>(chamfer_coop_kernel),
                             dim3(NBLK), dim3(512), args, 0, stream);
}

// Round 9
// 19.903 us; speedup vs baseline: 2.7349x; 2.7349x over previous
//
#include <hip/hip_runtime.h>

namespace {
constexpr int B_ = 4;
constexpr int N_ = 240 * 320;      // 76800 pixels per image (C == 1)
constexpr int M_ = 256;            // bins
constexpr int PXB = 1024;          // pixels per block
constexpr int CHUNKS = N_ / PXB;   // 75 blocks per batch
constexpr int NBLK = B_ * CHUNKS;  // 300 blocks
constexpr int NI = M_ + 1;         // 257 value-intervals
constexpr float BIG = 3.0e38f;
constexpr unsigned POISON = 0xAAAAAAAAu;

// ws words. Plain slots overwritten every call (deterministic).
//   WS_T2B  [NBLK]   per-block t2b partial sums   (plain store)
//   WS_MAXP [NBLK]   per-block pixel maxima       (plain store)
//   WS_SORT [B_*M_]  sorted bins                  (plain store, chunk-0 blocks)
//   WS_GMIN [B_*NI]  per-interval min pixel bits  (atomicMin; harness poison
//       0xAAAAAAAA > any +float bits -> acts as empty; idempotent on replays)
//   WS_GMAX [B_*NI]  NEGATED max pixel bits       (atomicMax; poison loses too)
constexpr int WS_T2B = 0;
constexpr int WS_MAXP = NBLK;
constexpr int WS_SORT = 2 * NBLK;
constexpr int WS_GMIN = 2 * NBLK + B_ * M_;
constexpr int WS_GMAX = WS_GMIN + B_ * NI;
}  // namespace

// Raw-value math: (c/m - t/m)^2 == (c-t)^2 / m^2; normalization deferred to
// the finisher (validated R5-R8: absmax 0.0).
__global__ __launch_bounds__(512) void chamfer_px_kernel(const float* __restrict__ target,
                                                         const float* __restrict__ bins,
                                                         unsigned* __restrict__ wsu) {
  float* wsf = reinterpret_cast<float*>(wsu);
  const int bid = blockIdx.x;
  const int b = bid / CHUNKS;
  const int chunk = bid - b * CHUNKS;
  const int tid = threadIdx.x;

  __shared__ __align__(16) float raw[M_];
  __shared__ float sbin[M_];
  __shared__ unsigned imin[NI], imax[NI];
  __shared__ float red[16];

  if (tid < M_) raw[tid] = bins[b * M_ + tid];
  for (int i = tid; i < NI; i += 512) {
    imin[i] = 0x7f800000u;  // +inf bits
    imax[i] = 0u;           // 0.0 bits (all pixels > 0)
  }
  __syncthreads();

  // ---- rank sort, 2 threads per bin (each counts one half; shfl combine) ----
  {
    const int bin = tid >> 1;
    const int half = tid & 1;
    const float myv = raw[bin];
    int rank = 0;
    const float4* r4 = reinterpret_cast<const float4*>(raw + half * 128);
#pragma unroll 4
    for (int k4 = 0; k4 < 32; ++k4) {
      const float4 v = r4[k4];  // LDS broadcast
      const int k = half * 128 + k4 * 4;
      rank += (v.x < myv || (v.x == myv && k + 0 < bin)) ? 1 : 0;
      rank += (v.y < myv || (v.y == myv && k + 1 < bin)) ? 1 : 0;
      rank += (v.z < myv || (v.z == myv && k + 2 < bin)) ? 1 : 0;
      rank += (v.w < myv || (v.w == myv && k + 3 < bin)) ? 1 : 0;
    }
    rank += __shfl_xor(rank, 1);  // partner lane holds the other half's count
    if (half == 0) sbin[rank] = myv;
  }
  __syncthreads();

  // ---- per-pixel: binary search -> flank distances + interval min/max ----
  const float2 px =
      reinterpret_cast<const float2*>(target + b * N_ + chunk * PXB)[tid];

  float ssum = 0.f;
#pragma unroll
  for (int e = 0; e < 2; ++e) {
    const float t = (e == 0) ? px.x : px.y;
    int pos = 0;  // count of bins <= t  (0..256)
#pragma unroll
    for (int step = 128; step > 0; step >>= 1)
      if (sbin[pos + step - 1] <= t) pos += step;
    if (pos < M_ && sbin[pos] <= t) ++pos;
    // nearest bin is one of the two flanks (sorted => exact)
    float dl = BIG, dr = BIG;
    if (pos > 0)  { const float d = t - sbin[pos - 1]; dl = d * d; }
    if (pos < M_) { const float d = sbin[pos] - t;     dr = d * d; }
    ssum += fminf(dl, dr);
    atomicMin(&imin[pos], __float_as_uint(t));
    atomicMax(&imax[pos], __float_as_uint(t));
  }

  float mx = fmaxf(px.x, px.y);
#pragma unroll
  for (int o = 32; o > 0; o >>= 1) {
    ssum += __shfl_down(ssum, o);
    mx = fmaxf(mx, __shfl_down(mx, o));
  }
  if ((tid & 63) == 0) {
    red[tid >> 6] = ssum;
    red[8 + (tid >> 6)] = mx;
  }
  __syncthreads();

  if (tid == 0) {
    float s = 0.f, m = 0.f;
#pragma unroll
    for (int w = 0; w < 8; ++w) {
      s += red[w];
      m = fmaxf(m, red[8 + w]);
    }
    wsf[WS_T2B + bid] = s;
    wsf[WS_MAXP + bid] = m;
  }

  // flush block-local interval extrema to per-batch global slots
  for (int i = tid; i < NI; i += 512) {
    const unsigned mn = imin[i];
    if (mn != 0x7f800000u) atomicMin(&wsu[WS_GMIN + b * NI + i], mn);
    const unsigned mb = imax[i];
    if (mb != 0u)
      atomicMax(&wsu[WS_GMAX + b * NI + i],
                __float_as_uint(-__uint_as_float(mb)));  // negate: max as uint-max
  }
  if (chunk == 0 && tid < M_) wsf[WS_SORT + b * M_ + tid] = sbin[tid];
}

// One block; kernel boundary = global barrier. Register scans, 3 barriers total.
__global__ __launch_bounds__(1024) void chamfer_final_kernel(const unsigned* __restrict__ wsu,
                                                             float* __restrict__ out) {
  const float* wsf = reinterpret_cast<const float*>(wsu);
  const int tid = threadIdx.x;
  const int bh = tid >> 8;      // batch 0..3 (each = 4 consecutive waves)
  const int j = tid & 255;      // bin rank within batch
  const int lane = tid & 63;
  const int wave = tid >> 6;    // 0..15
  const int lw = wave & 3;      // wave index within batch
  const int wb = wave & ~3;     // first wave of this batch

  __shared__ float wagg[16], sagg[16];
  __shared__ float red[48];

  // seeds: below-candidate = interval_max[j]; above-candidate = interval_min[j+1]
  float v, s;
  {
    const unsigned u = wsu[WS_GMAX + bh * NI + j];
    v = (u == POISON) ? -BIG : -__uint_as_float(u);
    const unsigned w2 = wsu[WS_GMIN + bh * NI + j + 1];
    s = (w2 == POISON) ? BIG : __uint_as_float(w2);
  }
  const float c = wsf[WS_SORT + bh * M_ + j];

  // wave-level inclusive prefix-max (v) and suffix-min (s)
#pragma unroll
  for (int o = 1; o <= 32; o <<= 1) {
    const float up = __shfl_up(v, o);
    if (lane >= o) v = fmaxf(v, up);
    const float dn = __shfl_down(s, o);
    if (lane + o < 64) s = fminf(s, dn);
  }
  if (lane == 63) wagg[wave] = v;  // wave max (prefix aggregate)
  if (lane == 0) sagg[wave] = s;   // wave min (suffix aggregate)
  __syncthreads();
  // cross-wave: earlier waves' maxima into v, later waves' minima into s
#pragma unroll
  for (int p = 0; p < 3; ++p) {
    if (p < lw) v = fmaxf(v, wagg[wb + p]);
    if (lw + 1 + p < 4) s = fminf(s, sagg[wb + lw + 1 + p]);
  }

  // bin j: below = max pixel <= c (intervals 0..j), above = min pixel > region
  const float d1 = (v == -BIG) ? BIG : (c - v) * (c - v);
  const float d2 = (s == BIG) ? BIG : (s - c) * (s - c);
  float vb = fminf(d1, d2);

  float st = (j < CHUNKS) ? wsf[WS_T2B + bh * CHUNKS + j] : 0.f;
  float sx = (j < CHUNKS) ? wsf[WS_MAXP + bh * CHUNKS + j] : 0.f;
#pragma unroll
  for (int o = 32; o > 0; o >>= 1) {
    vb += __shfl_down(vb, o);
    st += __shfl_down(st, o);
    sx = fmaxf(sx, __shfl_down(sx, o));
  }
  if (lane == 0) {
    red[wave] = vb;
    red[16 + wave] = st;
    red[32 + wave] = sx;
  }
  __syncthreads();
  if (tid == 0) {
    float loss = 0.f;
#pragma unroll
    for (int bat = 0; bat < B_; ++bat) {
      float s1 = 0.f, s2 = 0.f, m = 0.f;
#pragma unroll
      for (int w = 0; w < 4; ++w) {
        s1 += red[bat * 4 + w];
        s2 += red[16 + bat * 4 + w];
        m = fmaxf(m, red[32 + bat * 4 + w]);
      }
      const float inv = 1.0f / (m * m);  // deferred normalization
      loss += (s1 / (float)M_) * inv + (s2 / (float)N_) * inv;
    }
    out[0] = loss / (float)B_ * 10.0f;
  }
}

extern "C" void kernel_launch(void* const* d_in, const int* in_sizes, int n_in,
                              void* d_out, int out_size, void* d_ws, size_t ws_size,
                              hipStream_t stream) {
  (void)in_sizes; (void)n_in; (void)out_size; (void)ws_size;
  const float* target = reinterpret_cast<const float*>(d_in[0]);
  const float* bins = reinterpret_cast<const float*>(d_in[1]);
  unsigned* ws = reinterpret_cast<unsigned*>(d_ws);
  float* out = reinterpret_cast<float*>(d_out);

  chamfer_px_kernel<<<NBLK, 512, 0, stream>>>(target, bins, ws);
  chamfer_final_kernel<<<1, 1024, 0, stream>>>(ws, out);
}

// Round 10
// 17.717 us; speedup vs baseline: 3.0722x; 1.1234x over previous
//
#include <hip/hip_runtime.h>

namespace {
constexpr int B_ = 4;
constexpr int N_ = 240 * 320;      // 76800 pixels per image (C == 1)
constexpr int M_ = 256;            // bins
constexpr int PXB = 1280;          // pixels per block (640 threads x float2)
constexpr int CHUNKS = N_ / PXB;   // 60 blocks per batch
constexpr int NBLK = B_ * CHUNKS;  // 240 blocks -> one per CU, single dispatch wave
constexpr int NT = 640;            // threads per block (10 waves)
constexpr int NI = M_ + 1;         // 257 value-intervals
constexpr float BIG = 3.0e38f;
constexpr unsigned POISON = 0xAAAAAAAAu;

// ws words. Plain slots overwritten every call (deterministic).
//   WS_T2B  [NBLK]   per-block t2b partial sums   (plain store)
//   WS_MAXP [NBLK]   per-block pixel maxima       (plain store)
//   WS_SORT [B_*M_]  sorted bins                  (plain store, chunk-0 blocks)
//   WS_GMIN [B_*NI]  per-interval min pixel bits  (atomicMin; harness poison
//       0xAAAAAAAA > any +float bits -> acts as empty; idempotent on replays)
//   WS_GMAX [B_*NI]  NEGATED max pixel bits       (atomicMax; poison loses too)
constexpr int WS_T2B = 0;
constexpr int WS_MAXP = NBLK;
constexpr int WS_SORT = 2 * NBLK;
constexpr int WS_GMIN = 2 * NBLK + B_ * M_;
constexpr int WS_GMAX = WS_GMIN + B_ * NI;
}  // namespace

// Raw-value math: (c/m - t/m)^2 == (c-t)^2 / m^2; normalization deferred to
// the finisher (validated R5-R9: absmax 0.0).
__global__ __launch_bounds__(NT) void chamfer_px_kernel(const float* __restrict__ target,
                                                        const float* __restrict__ bins,
                                                        unsigned* __restrict__ wsu) {
  float* wsf = reinterpret_cast<float*>(wsu);
  const int bid = blockIdx.x;
  const int b = bid / CHUNKS;
  const int chunk = bid - b * CHUNKS;
  const int tid = threadIdx.x;

  __shared__ __align__(16) float raw[M_];
  __shared__ float sbin[M_];
  __shared__ unsigned imin[NI], imax[NI];
  __shared__ float red[20];

  if (tid < M_) raw[tid] = bins[b * M_ + tid];
  for (int i = tid; i < NI; i += NT) {
    imin[i] = 0x7f800000u;  // +inf bits
    imax[i] = 0u;           // 0.0 bits (all pixels > 0)
  }
  __syncthreads();

  // ---- rank sort, 2 threads per bin (threads 0..511; shfl combine) ----
  if (tid < 512) {
    const int bin = tid >> 1;
    const int half = tid & 1;
    const float myv = raw[bin];
    int rank = 0;
    const float4* r4 = reinterpret_cast<const float4*>(raw + half * 128);
#pragma unroll 4
    for (int k4 = 0; k4 < 32; ++k4) {
      const float4 v = r4[k4];  // LDS broadcast
      const int k = half * 128 + k4 * 4;
      rank += (v.x < myv || (v.x == myv && k + 0 < bin)) ? 1 : 0;
      rank += (v.y < myv || (v.y == myv && k + 1 < bin)) ? 1 : 0;
      rank += (v.z < myv || (v.z == myv && k + 2 < bin)) ? 1 : 0;
      rank += (v.w < myv || (v.w == myv && k + 3 < bin)) ? 1 : 0;
    }
    rank += __shfl_xor(rank, 1);  // partner lane has the other half's count
    if (half == 0) sbin[rank] = myv;
  }
  __syncthreads();

  // ---- per-pixel: binary search -> flank distances + interval min/max ----
  const float2 px =
      reinterpret_cast<const float2*>(target + b * N_ + chunk * PXB)[tid];

  float ssum = 0.f;
#pragma unroll
  for (int e = 0; e < 2; ++e) {
    const float t = (e == 0) ? px.x : px.y;
    int pos = 0;  // count of bins <= t  (0..256)
#pragma unroll
    for (int step = 128; step > 0; step >>= 1)
      if (sbin[pos + step - 1] <= t) pos += step;
    if (pos < M_ && sbin[pos] <= t) ++pos;
    // nearest bin is one of the two flanks (sorted => exact)
    float dl = BIG, dr = BIG;
    if (pos > 0)  { const float d = t - sbin[pos - 1]; dl = d * d; }
    if (pos < M_) { const float d = sbin[pos] - t;     dr = d * d; }
    ssum += fminf(dl, dr);
    atomicMin(&imin[pos], __float_as_uint(t));
    atomicMax(&imax[pos], __float_as_uint(t));
  }

  float mx = fmaxf(px.x, px.y);
#pragma unroll
  for (int o = 32; o > 0; o >>= 1) {
    ssum += __shfl_down(ssum, o);
    mx = fmaxf(mx, __shfl_down(mx, o));
  }
  if ((tid & 63) == 0) {
    red[tid >> 6] = ssum;
    red[10 + (tid >> 6)] = mx;
  }
  __syncthreads();

  if (tid == 0) {
    float s = 0.f, m = 0.f;
#pragma unroll
    for (int w = 0; w < 10; ++w) {
      s += red[w];
      m = fmaxf(m, red[10 + w]);
    }
    wsf[WS_T2B + bid] = s;
    wsf[WS_MAXP + bid] = m;
  }

  // flush block-local interval extrema to per-batch global slots
  for (int i = tid; i < NI; i += NT) {
    const unsigned mn = imin[i];
    if (mn != 0x7f800000u) atomicMin(&wsu[WS_GMIN + b * NI + i], mn);
    const unsigned mb = imax[i];
    if (mb != 0u)
      atomicMax(&wsu[WS_GMAX + b * NI + i],
                __float_as_uint(-__uint_as_float(mb)));  // negate: max as uint-max
  }
  if (chunk == 0 && tid < M_) wsf[WS_SORT + b * M_ + tid] = sbin[tid];
}

// One block; kernel boundary = global barrier. Register scans, 2 barriers.
__global__ __launch_bounds__(1024) void chamfer_final_kernel(const unsigned* __restrict__ wsu,
                                                             float* __restrict__ out) {
  const float* wsf = reinterpret_cast<const float*>(wsu);
  const int tid = threadIdx.x;
  const int bh = tid >> 8;      // batch 0..3 (each = 4 consecutive waves)
  const int j = tid & 255;      // bin rank within batch
  const int lane = tid & 63;
  const int wave = tid >> 6;    // 0..15
  const int lw = wave & 3;      // wave index within batch
  const int wb = wave & ~3;     // first wave of this batch

  __shared__ float wagg[16], sagg[16];
  __shared__ float red[48];

  // seeds: below-candidate = interval_max[j]; above-candidate = interval_min[j+1]
  float v, s;
  {
    const unsigned u = wsu[WS_GMAX + bh * NI + j];
    v = (u == POISON) ? -BIG : -__uint_as_float(u);
    const unsigned w2 = wsu[WS_GMIN + bh * NI + j + 1];
    s = (w2 == POISON) ? BIG : __uint_as_float(w2);
  }
  const float c = wsf[WS_SORT + bh * M_ + j];

  // wave-level inclusive prefix-max (v) and suffix-min (s)
#pragma unroll
  for (int o = 1; o <= 32; o <<= 1) {
    const float up = __shfl_up(v, o);
    if (lane >= o) v = fmaxf(v, up);
    const float dn = __shfl_down(s, o);
    if (lane + o < 64) s = fminf(s, dn);
  }
  if (lane == 63) wagg[wave] = v;  // wave max (prefix aggregate)
  if (lane == 0) sagg[wave] = s;   // wave min (suffix aggregate)
  __syncthreads();
  // cross-wave: earlier waves' maxima into v, later waves' minima into s
#pragma unroll
  for (int p = 0; p < 3; ++p) {
    if (p < lw) v = fmaxf(v, wagg[wb + p]);
    if (lw + 1 + p < 4) s = fminf(s, sagg[wb + lw + 1 + p]);
  }

  // bin j: below = max pixel in intervals 0..j, above = min pixel in j+1..256
  const float d1 = (v == -BIG) ? BIG : (c - v) * (c - v);
  const float d2 = (s == BIG) ? BIG : (s - c) * (s - c);
  float vb = fminf(d1, d2);

  float st = (j < CHUNKS) ? wsf[WS_T2B + bh * CHUNKS + j] : 0.f;
  float sx = (j < CHUNKS) ? wsf[WS_MAXP + bh * CHUNKS + j] : 0.f;
#pragma unroll
  for (int o = 32; o > 0; o >>= 1) {
    vb += __shfl_down(vb, o);
    st += __shfl_down(st, o);
    sx = fmaxf(sx, __shfl_down(sx, o));
  }
  if (lane == 0) {
    red[wave] = vb;
    red[16 + wave] = st;
    red[32 + wave] = sx;
  }
  __syncthreads();
  if (tid == 0) {
    float loss = 0.f;
#pragma unroll
    for (int bat = 0; bat < B_; ++bat) {
      float s1 = 0.f, s2 = 0.f, m = 0.f;
#pragma unroll
      for (int w = 0; w < 4; ++w) {
        s1 += red[bat * 4 + w];
        s2 += red[16 + bat * 4 + w];
        m = fmaxf(m, red[32 + bat * 4 + w]);
      }
      const float inv = 1.0f / (m * m);  // deferred normalization
      loss += (s1 / (float)M_) * inv + (s2 / (float)N_) * inv;
    }
    out[0] = loss / (float)B_ * 10.0f;
  }
}

extern "C" void kernel_launch(void* const* d_in, const int* in_sizes, int n_in,
                              void* d_out, int out_size, void* d_ws, size_t ws_size,
                              hipStream_t stream) {
  (void)in_sizes; (void)n_in; (void)out_size; (void)ws_size;
  const float* target = reinterpret_cast<const float*>(d_in[0]);
  const float* bins = reinterpret_cast<const float*>(d_in[1]);
  unsigned* ws = reinterpret_cast<unsigned*>(d_ws);
  float* out = reinterpret_cast<float*>(d_out);

  chamfer_px_kernel<<<NBLK, NT, 0, stream>>>(target, bins, ws);
  chamfer_final_kernel<<<1, 1024, 0, stream>>>(ws, out);
}